// Round 3
// baseline (445.788 us; speedup 1.0000x reference)
//
#include <hip/hip_runtime.h>
#include <hip/hip_bf16.h>

typedef unsigned short u16;
typedef unsigned short u16x8 __attribute__((ext_vector_type(8)));
typedef __bf16 bf16x8 __attribute__((ext_vector_type(8)));
typedef float f32x4 __attribute__((ext_vector_type(4)));

#define LRS 0.2f

__device__ __forceinline__ u16 f2b(float f) {
  __hip_bfloat16 h = __float2bfloat16(f);
  return __builtin_bit_cast(u16, h);
}

// ---------------------------------------------------------------------------
// Generic: 4 rows (staged in LDS f32, rows at stride K) x W[O][K] f32 -> y[4][O]
// KSEG threads cooperate along K (shfl reduce), 256/KSEG outputs per pass.
// ---------------------------------------------------------------------------
template<int K, int O, int KSEG>
__device__ __forceinline__ void gemm_rows4(const float* xr, const float* W, const float* bias,
                                           float* yl, float* yg, int ygstride) {
  constexpr int KPT = K / KSEG;
  constexpr int OPP = 256 / KSEG;
  const int t = threadIdx.x;
  const int ks = t % KSEG;
  const int oi = t / KSEG;
#pragma unroll
  for (int pass = 0; pass < O / OPP; ++pass) {
    const int o = pass * OPP + oi;
    float a0 = 0, a1 = 0, a2 = 0, a3 = 0;
    const float* wp = W + (size_t)o * K + ks * KPT;
    const float* xb = xr + ks * KPT;
#pragma unroll 4
    for (int kc = 0; kc < KPT; kc += 4) {
      f32x4 w4 = *(const f32x4*)(wp + kc);
      const float* xp = xb + kc;
#pragma unroll
      for (int j = 0; j < 4; ++j) {
        float w = w4[j];
        a0 += xp[j] * w;
        a1 += xp[K + j] * w;
        a2 += xp[2 * K + j] * w;
        a3 += xp[3 * K + j] * w;
      }
    }
#pragma unroll
    for (int d = 1; d < KSEG; d <<= 1) {
      a0 += __shfl_xor(a0, d, 64);
      a1 += __shfl_xor(a1, d, 64);
      a2 += __shfl_xor(a2, d, 64);
      a3 += __shfl_xor(a3, d, 64);
    }
    if (ks == 0) {
      float bv = bias ? bias[o] : 0.0f;
      float v0 = a0 + bv, v1 = a1 + bv, v2 = a2 + bv, v3 = a3 + bv;
      if (yl) { yl[o] = v0; yl[O + o] = v1; yl[2 * O + o] = v2; yl[3 * O + o] = v3; }
      if (yg) { yg[o] = v0; yg[ygstride + o] = v1; yg[2 * (size_t)ygstride + o] = v2; yg[3 * (size_t)ygstride + o] = v3; }
    }
  }
}

// ---------------------------------------------------------------------------
// W1: fold weights.  Mfull[hf][c] = sum_e edge_w[f,e]*We2_w[h*16+e,c]
//     vb[c][h] = bf16( sum_e We_w[h*16+e,c]*a_e[e] )   (B-frag matrix for se)
//     cbe[hf]  = sum_e We2_b[h*16+e]*edge_w[f,e] + edge_b[f]
//     sconst[h]= sum_e We_b[h*16+e]*a_e[e]
// ---------------------------------------------------------------------------
__global__ __launch_bounds__(256) void kW1(const float* We_w, const float* We_b, const float* attn,
                                           const float* We2_w, const float* We2_b,
                                           const float* edge_w, const float* edge_b,
                                           float* Mfull, u16* vb, float* cbe, float* sconst) {
  int gid = blockIdx.x * 256 + threadIdx.x;
  if (gid < 16384) {
    int hf = gid >> 7, c = gid & 127;
    int h = hf >> 4, fo = hf & 15;
    float s = 0;
    for (int e = 0; e < 16; ++e)
      s += edge_w[fo * 176 + e] * We2_w[(h * 16 + e) * 128 + c];
    Mfull[hf * 128 + c] = s;
  } else if (gid < 16384 + 2048) {
    int idx = gid - 16384;
    int c = idx >> 4, hc = idx & 15;
    float s = 0;
    if (hc < 8)
      for (int e = 0; e < 16; ++e)
        s += We_w[(hc * 16 + e) * 128 + c] * attn[128 + e];
    vb[c * 16 + hc] = f2b(s);
  } else if (gid < 18432 + 128) {
    int hf = gid - 18432;
    int h = hf >> 4, fo = hf & 15;
    float s = edge_b[fo];
    for (int e = 0; e < 16; ++e)
      s += We2_b[h * 16 + e] * edge_w[fo * 176 + e];
    cbe[hf] = s;
  } else if (gid < 18560 + 8) {
    int h = gid - 18560;
    float s = 0;
    for (int e = 0; e < 16; ++e)
      s += We_b[h * 16 + e] * attn[128 + e];
    sconst[h] = s;
  }
}

// W2: G[o][c] = sum_k oute_w[o,k]*Mfull[k][c], stored bf16 row-major (o,c)
__global__ __launch_bounds__(256) void kW2(const float* oute_w, const float* Mfull, u16* Gb) {
  int gid = blockIdx.x * 256 + threadIdx.x;
  int o = gid >> 7, c = gid & 127;
  float s = 0;
  for (int k = 0; k < 128; ++k)
    s += oute_w[o * 128 + k] * Mfull[k * 128 + c];
  Gb[o * 128 + c] = f2b(s);
}

// ---------------------------------------------------------------------------
// N1: per 4 node-rows: npj, dpj, node_wh, srow, scol
// ---------------------------------------------------------------------------
__global__ __launch_bounds__(256) void kN1(const float* node, const float* diff,
                                           const float* Wn_w, const float* Wn_b,
                                           const float* Wd_w, const float* Wd_b,
                                           const float* Wh_w, const float* Wh_b,
                                           const float* attn, const float* sconst,
                                           float* npj_g, float* nwh_g,
                                           float* srow_g, float* scol_g) {
  __shared__ float nrow[4 * 512], npjl[4 * 512], drow[4 * 128], dpjl[4 * 128];
  const int t = threadIdx.x;
  const int r0 = blockIdx.x * 4;
  *(f32x4*)&nrow[t * 8]     = *(const f32x4*)(node + (size_t)r0 * 512 + t * 8);
  *(f32x4*)&nrow[t * 8 + 4] = *(const f32x4*)(node + (size_t)r0 * 512 + t * 8 + 4);
  if (t < 64) {
    *(f32x4*)&drow[t * 8]     = *(const f32x4*)(diff + (size_t)r0 * 128 + t * 8);
    *(f32x4*)&drow[t * 8 + 4] = *(const f32x4*)(diff + (size_t)r0 * 128 + t * 8 + 4);
  }
  __syncthreads();
  gemm_rows4<512, 512, 4>(nrow, Wn_w, Wn_b, npjl, npj_g + (size_t)r0 * 512, 512);
  gemm_rows4<128, 128, 4>(drow, Wd_w, Wd_b, dpjl, nullptr, 0);
  __syncthreads();
  // node_wh (per-head 64x64, same Wh for all heads)
  {
    int d = t & 63, hh = t >> 6;
#pragma unroll
    for (int hi = 0; hi < 2; ++hi) {
      int h = hh + hi * 4;
      float wb = Wh_b[d];
      float acc[4] = {wb, wb, wb, wb};
      for (int k = 0; k < 64; ++k) {
        float w = Wh_w[d * 64 + k];
#pragma unroll
        for (int r = 0; r < 4; ++r) acc[r] += npjl[r * 512 + h * 64 + k] * w;
      }
#pragma unroll
      for (int r = 0; r < 4; ++r) nwh_g[(size_t)(r0 + r) * 512 + h * 64 + d] = acc[r];
    }
  }
  if (t < 32) {
    int r = t >> 3, h = t & 7;
    float shi = 0, shj = 0, sdi = 0, sdj = 0;
    for (int d = 0; d < 64; ++d) {
      float x = npjl[r * 512 + h * 64 + d];
      shi += x * attn[d];
      shj += x * attn[64 + d];
    }
    for (int e = 0; e < 16; ++e) {
      float x = dpjl[r * 128 + h * 16 + e];
      sdi += x * attn[144 + e];
      sdj += x * attn[160 + e];
    }
    srow_g[(r0 + r) * 8 + h] = shi + sdi + sconst[h];
    scol_g[(r0 + r) * 8 + h] = shj + sdj;
  }
}

// ---------------------------------------------------------------------------
// A: per (b,l): se via MFMA (edge row x v), lrelu+softmax, agg, new_node_pre
// ---------------------------------------------------------------------------
__global__ __launch_bounds__(256) void kA(const float* edge, const float* npj, const float* nwh,
                                          const float* srow, const float* scol,
                                          const u16* vb, float* nnp) {
  __shared__ float s_arr[512][9];
  __shared__ float red[256];
  __shared__ float mxh[8], inv8[8];
  __shared__ float part[2][512];
  const int bl = blockIdx.x;
  const int b = bl >> 9, l = bl & 511;
  const int t = threadIdx.x;
  const int w = t >> 6, lane = t & 63;
  const int colL = lane & 15, kg = lane >> 4;
  // B-fragments: B[k=c][col=h] = vb[c][h]
  bf16x8 bfr[4];
#pragma unroll
  for (int ks = 0; ks < 4; ++ks) {
    u16x8 u;
#pragma unroll
    for (int j = 0; j < 8; ++j) u[j] = vb[(ks * 32 + kg * 8 + j) * 16 + colL];
    bfr[ks] = __builtin_bit_cast(bf16x8, u);
  }
  float srh = (colL < 8) ? srow[(size_t)bl * 8 + colL] : 0.0f;
  const float* erow = edge + (size_t)bl * 512 * 128;
  for (int fr = 0; fr < 8; ++fr) {
    int m0 = w * 128 + fr * 16;
    f32x4 acc = {0, 0, 0, 0};
#pragma unroll
    for (int ks = 0; ks < 4; ++ks) {
      const float* ep = erow + (size_t)(m0 + colL) * 128 + ks * 32 + kg * 8;
      f32x4 e0 = *(const f32x4*)(ep);
      f32x4 e1 = *(const f32x4*)(ep + 4);
      u16x8 a8;
#pragma unroll
      for (int j = 0; j < 4; ++j) { a8[j] = f2b(e0[j]); a8[4 + j] = f2b(e1[j]); }
      acc = __builtin_amdgcn_mfma_f32_16x16x32_bf16(__builtin_bit_cast(bf16x8, a8), bfr[ks], acc, 0, 0, 0);
    }
    if (colL < 8) {
#pragma unroll
      for (int r = 0; r < 4; ++r) {
        int m = m0 + kg * 4 + r;
        float sv = acc[r] + srh + scol[((size_t)b * 512 + m) * 8 + colL];
        sv = (m == l) ? -__builtin_inff() : (sv >= 0.0f ? sv : LRS * sv);
        s_arr[m][colL] = sv;
      }
    }
  }
  __syncthreads();
  const int h = t & 7, seg = t >> 3;
  float mx = -__builtin_inff();
#pragma unroll 4
  for (int i = 0; i < 16; ++i) mx = fmaxf(mx, s_arr[seg * 16 + i][h]);
  red[t] = mx;
  __syncthreads();
  if (t < 8) {
    float m2 = -__builtin_inff();
    for (int sg = 0; sg < 32; ++sg) m2 = fmaxf(m2, red[sg * 8 + t]);
    mxh[t] = m2;
  }
  __syncthreads();
  float mh = mxh[h];
  float sm = 0;
#pragma unroll 4
  for (int i = 0; i < 16; ++i) {
    int m = seg * 16 + i;
    float p = __expf(s_arr[m][h] - mh);
    s_arr[m][h] = p;
    sm += p;
  }
  red[t] = sm;
  __syncthreads();
  if (t < 8) {
    float s2 = 0;
    for (int sg = 0; sg < 32; ++sg) s2 += red[sg * 8 + t];
    inv8[t] = 1.0f / s2;
  }
  __syncthreads();
  // agg[o] = sum_m p[m][h]*node_wh[b,m,o], split m into 2 halves
  const int half = t >> 7, oq = t & 127;
  const int o4 = oq * 4, hh = oq >> 4;
  f32x4 acc4 = {0, 0, 0, 0};
  const float* nb = nwh + (size_t)b * 512 * 512;
  for (int m = half * 256; m < half * 256 + 256; ++m) {
    float p = s_arr[m][hh];
    f32x4 nv = *(const f32x4*)(nb + (size_t)m * 512 + o4);
    acc4 += p * nv;
  }
  *(f32x4*)&part[half][o4] = acc4;
  __syncthreads();
  if (t < 128) {
    int ob = t * 4, h2 = t >> 4;
    f32x4 s0 = *(f32x4*)&part[0][ob];
    f32x4 s1 = *(f32x4*)&part[1][ob];
    f32x4 np4 = *(const f32x4*)(npj + (size_t)bl * 512 + ob);
    float iv = inv8[h2];
    f32x4 o;
#pragma unroll
    for (int j = 0; j < 4; ++j) {
      float a = (s0[j] + s1[j]) * iv;
      a = a >= 0.0f ? a : LRS * a;
      o[j] = np4[j] + a;
    }
    *(f32x4*)(nnp + (size_t)bl * 512 + ob) = o;
  }
}

// N2: new_node = nnp @ outn^T + b  -> f32 out (also serves as stage-2 input)
__global__ __launch_bounds__(256) void kN2(const float* nnp, const float* outn_w, const float* outn_b,
                                           float* out0) {
  __shared__ float xr[4 * 512];
  const int t = threadIdx.x;
  const int r0 = blockIdx.x * 4;
  *(f32x4*)&xr[t * 4]        = *(const f32x4*)(nnp + (size_t)r0 * 512 + t * 4);
  *(f32x4*)&xr[1024 + t * 4] = *(const f32x4*)(nnp + (size_t)r0 * 512 + 1024 + t * 4);
  __syncthreads();
  gemm_rows4<512, 512, 4>(xr, outn_w, outn_b, nullptr, out0 + (size_t)r0 * 512, 512);
}

// N3: np2, dp2, then Rl/Rm (with cbe folded into Rl)
__global__ __launch_bounds__(256) void kN3(const float* nn, const float* diff,
                                           const float* Wn2_w, const float* Wn2_b,
                                           const float* Wd2_w, const float* Wd2_b,
                                           const float* edge_w, const float* cbe,
                                           float* Rl_g, float* Rm_g) {
  __shared__ float xr[4 * 512], np2l[4 * 512], dr[4 * 128], dp2l[4 * 128];
  const int t = threadIdx.x;
  const int r0 = blockIdx.x * 4;
  *(f32x4*)&xr[t * 4]        = *(const f32x4*)(nn + (size_t)r0 * 512 + t * 4);
  *(f32x4*)&xr[1024 + t * 4] = *(const f32x4*)(nn + (size_t)r0 * 512 + 1024 + t * 4);
  if (t < 64) {
    *(f32x4*)&dr[t * 8]     = *(const f32x4*)(diff + (size_t)r0 * 128 + t * 8);
    *(f32x4*)&dr[t * 8 + 4] = *(const f32x4*)(diff + (size_t)r0 * 128 + t * 8 + 4);
  }
  __syncthreads();
  gemm_rows4<512, 512, 4>(xr, Wn2_w, Wn2_b, np2l, nullptr, 0);
  gemm_rows4<128, 128, 4>(dr, Wd2_w, Wd2_b, dp2l, nullptr, 0);
  __syncthreads();
  {
    int hf = t & 127, which = t >> 7;
    int h = hf >> 4, fo = hf & 15;
    const float* wh = edge_w + fo * 176 + 16 + which * 64;   // W_hi / W_hj
    const float* wd = edge_w + fo * 176 + 144 + which * 16;  // W_di / W_dj
    float add = which ? 0.0f : cbe[hf];
    float* dst = which ? Rm_g : Rl_g;
#pragma unroll
    for (int r = 0; r < 4; ++r) {
      float a = add;
      for (int d = 0; d < 64; ++d) a += np2l[r * 512 + h * 64 + d] * wh[d];
      for (int e = 0; e < 16; ++e) a += dp2l[r * 128 + h * 16 + e] * wd[e];
      dst[(size_t)(r0 + r) * 128 + hf] = a;
    }
  }
}

// N4: Pl = Rl@oute^T + oute_b ; Pm = Rm@oute^T
__global__ __launch_bounds__(256) void kN4(const float* Rl, const float* Rm,
                                           const float* oute_w, const float* oute_b,
                                           float* Pl, float* Pm) {
  __shared__ float xl[4 * 128], xm[4 * 128];
  const int t = threadIdx.x;
  const int r0 = blockIdx.x * 4;
  if (t < 128) *(f32x4*)&xl[t * 4] = *(const f32x4*)(Rl + (size_t)r0 * 128 + t * 4);
  else { int q = t - 128; *(f32x4*)&xm[q * 4] = *(const f32x4*)(Rm + (size_t)r0 * 128 + q * 4); }
  __syncthreads();
  gemm_rows4<128, 128, 4>(xl, oute_w, oute_b, nullptr, Pl + (size_t)r0 * 128, 128);
  gemm_rows4<128, 128, 4>(xm, oute_w, nullptr, nullptr, Pm + (size_t)r0 * 128, 128);
}

// ---------------------------------------------------------------------------
// E: new_edge[bl, m0+m, :] = edge_row @ G^T + Pl[bl] + Pm[b, m0+m]
// 128(m) x 128(o) tile, MFMA 16x16x32 bf16, XOR-swizzled LDS.
// ---------------------------------------------------------------------------
__global__ __launch_bounds__(256) void kE(const float* edge, const u16* Gb,
                                          const float* Pl, const float* Pm, float* oute) {
  __shared__ u16 At[16384];
  __shared__ u16 Gt[16384];
  const int tile = blockIdx.x;
  const int bl = tile >> 2;
  const int b = bl >> 9;
  const int m0 = (tile & 3) * 128;
  const int t = threadIdx.x, lane = t & 63, w = t >> 6;
  const float* Ab = edge + ((size_t)bl * 512 + m0) * 128;
#pragma unroll
  for (int j = 0; j < 8; ++j) {
    int u = j * 256 + t;
    int row = u >> 4, cu = u & 15;
    int su = row * 16 + (cu ^ (row & 7));
    f32x4 e0 = *(const f32x4*)(Ab + (size_t)row * 128 + cu * 8);
    f32x4 e1 = *(const f32x4*)(Ab + (size_t)row * 128 + cu * 8 + 4);
    u16x8 a8;
#pragma unroll
    for (int j2 = 0; j2 < 4; ++j2) { a8[j2] = f2b(e0[j2]); a8[4 + j2] = f2b(e1[j2]); }
    *(u16x8*)(At + su * 8) = a8;
    *(u16x8*)(Gt + su * 8) = *(const u16x8*)(Gb + u * 8);
  }
  __syncthreads();
  const int wr = w >> 1, wc = w & 1;
  const int colL = lane & 15, kg = lane >> 4;
  f32x4 acc[4][4] = {};
#pragma unroll
  for (int ks = 0; ks < 4; ++ks) {
    bf16x8 af[4], bfv[4];
    int cu = ks * 4 + kg;
#pragma unroll
    for (int i = 0; i < 4; ++i) {
      int row = wr * 64 + i * 16 + colL;
      af[i] = *(bf16x8*)(At + (row * 16 + (cu ^ (row & 7))) * 8);
      int orow = wc * 64 + i * 16 + colL;
      bfv[i] = *(bf16x8*)(Gt + (orow * 16 + (cu ^ (orow & 7))) * 8);
    }
#pragma unroll
    for (int i = 0; i < 4; ++i)
#pragma unroll
      for (int n = 0; n < 4; ++n)
        acc[i][n] = __builtin_amdgcn_mfma_f32_16x16x32_bf16(af[i], bfv[n], acc[i][n], 0, 0, 0);
  }
  const float* plp = Pl + (size_t)bl * 128;
  float plv[4];
#pragma unroll
  for (int n = 0; n < 4; ++n) plv[n] = plp[wc * 64 + n * 16 + colL];
  float* ob = oute + ((size_t)bl * 512 + m0) * 128;
#pragma unroll
  for (int i = 0; i < 4; ++i) {
#pragma unroll
    for (int r = 0; r < 4; ++r) {
      int m = wr * 64 + i * 16 + kg * 4 + r;
      const float* pmp = Pm + ((size_t)b * 512 + m0 + m) * 128;
#pragma unroll
      for (int n = 0; n < 4; ++n) {
        int o = wc * 64 + n * 16 + colL;
        ob[(size_t)m * 128 + o] = acc[i][n][r] + plv[n] + pmp[o];
      }
    }
  }
}

extern "C" void kernel_launch(void* const* d_in, const int* in_sizes, int n_in,
                              void* d_out, int out_size, void* d_ws, size_t ws_size,
                              hipStream_t stream) {
  (void)in_sizes; (void)n_in; (void)out_size; (void)ws_size;
  const float* node   = (const float*)d_in[0];
  const float* edge   = (const float*)d_in[1];
  const float* diff   = (const float*)d_in[2];
  const float* Wn_w   = (const float*)d_in[3];
  const float* Wn_b   = (const float*)d_in[4];
  const float* We_w   = (const float*)d_in[5];
  const float* We_b   = (const float*)d_in[6];
  const float* Wd_w   = (const float*)d_in[7];
  const float* Wd_b   = (const float*)d_in[8];
  const float* Wh_w   = (const float*)d_in[9];
  const float* Wh_b   = (const float*)d_in[10];
  const float* attn   = (const float*)d_in[11];
  const float* outn_w = (const float*)d_in[12];
  const float* outn_b = (const float*)d_in[13];
  const float* Wn2_w  = (const float*)d_in[14];
  const float* Wn2_b  = (const float*)d_in[15];
  const float* We2_w  = (const float*)d_in[16];
  const float* We2_b  = (const float*)d_in[17];
  const float* Wd2_w  = (const float*)d_in[18];
  const float* Wd2_b  = (const float*)d_in[19];
  const float* edge_w = (const float*)d_in[20];
  const float* edge_b = (const float*)d_in[21];
  const float* oute_w = (const float*)d_in[22];
  const float* oute_b = (const float*)d_in[23];

  float* out0 = (float*)d_out;           // new_node f32 (524288)
  float* out1 = out0 + 524288;           // new_edge f32

  float* f = (float*)d_ws;
  size_t off = 0;
  auto alloc = [&](size_t n) { float* p = f + off; off += (n + 7) & ~(size_t)7; return p; };
  float* npj    = alloc(524288);
  float* nwh    = alloc(524288);
  float* srow   = alloc(8192);
  float* scol   = alloc(8192);
  float* sconst = alloc(8);
  float* cbe    = alloc(128);
  float* Mfull  = alloc(16384);
  float* nnp    = alloc(524288);
  float* Rl     = alloc(131072);
  float* Rm     = alloc(131072);
  float* Pl     = alloc(131072);
  float* Pm     = alloc(131072);
  u16* vb = (u16*)(f + off); off += 1024;   // 2048 u16
  u16* Gb = (u16*)(f + off); off += 8192;   // 16384 u16

  hipLaunchKernelGGL(kW1, dim3(73), dim3(256), 0, stream,
                     We_w, We_b, attn, We2_w, We2_b, edge_w, edge_b, Mfull, vb, cbe, sconst);
  hipLaunchKernelGGL(kW2, dim3(64), dim3(256), 0, stream, oute_w, Mfull, Gb);
  hipLaunchKernelGGL(kN1, dim3(256), dim3(256), 0, stream,
                     node, diff, Wn_w, Wn_b, Wd_w, Wd_b, Wh_w, Wh_b, attn, sconst,
                     npj, nwh, srow, scol);
  hipLaunchKernelGGL(kA, dim3(1024), dim3(256), 0, stream,
                     edge, npj, nwh, srow, scol, vb, nnp);
  hipLaunchKernelGGL(kN2, dim3(256), dim3(256), 0, stream, nnp, outn_w, outn_b, out0);
  hipLaunchKernelGGL(kN3, dim3(256), dim3(256), 0, stream,
                     out0, diff, Wn2_w, Wn2_b, Wd2_w, Wd2_b, edge_w, cbe, Rl, Rm);
  hipLaunchKernelGGL(kN4, dim3(256), dim3(256), 0, stream, Rl, Rm, oute_w, oute_b, Pl, Pm);
  hipLaunchKernelGGL(kE, dim3(4096), dim3(256), 0, stream, edge, Gb, Pl, Pm, out1);
}